// Round 7
// baseline (490.698 us; speedup 1.0000x reference)
//
#include <hip/hip_runtime.h>

#define IN_DIM 256
#define HID 256
#define PADW 264   // 256 + 16 ushort pad

typedef unsigned short ushort_t;
typedef __attribute__((ext_vector_type(8))) short short8;
typedef __attribute__((ext_vector_type(4))) float floatx4;

__device__ __forceinline__ float b2f(ushort_t h) {
    union { unsigned int u; float f; } c; c.u = ((unsigned int)h) << 16; return c.f;
}
__device__ __forceinline__ ushort_t f2b(float f) {  // round-to-nearest-even
    union { float f; unsigned int u; } c; c.f = f;
    unsigned int u = c.u;
    unsigned int r = (u + 0x7fffu + ((u >> 16) & 1u)) >> 16;
    return (ushort_t)r;
}

// ---------------- fused: degree+slot count (atomic pass) | x -> bf16 cast ------------------
// Blocks [0, CB): pos_e[e] = atomicAdd(&deg[dst[e]], 1)   (latency-bound)
// Blocks [CB, CB+XB): float4 -> ushort4 cast              (BW-bound) — good co-schedule.
__global__ __launch_bounds__(256) void k_count_cast(const int* __restrict__ dst,
                                                    int* __restrict__ deg,
                                                    int* __restrict__ pos_e, int E, int CB,
                                                    const float* __restrict__ x,
                                                    ushort_t* __restrict__ xb, int n4) {
    int b = blockIdx.x;
    if (b < CB) {
        int e = b * 256 + threadIdx.x;
        if (e < E) pos_e[e] = atomicAdd(&deg[dst[e]], 1);
    } else {
        int i = (b - CB) * 256 + threadIdx.x;
        if (i < n4) {
            float4 v = ((const float4*)x)[i];
            ushort4 o;
            o.x = f2b(v.x); o.y = f2b(v.y); o.z = f2b(v.z); o.w = f2b(v.w);
            ((ushort4*)xb)[i] = o;
        }
    }
}

// ---------------- single-kernel exclusive scan: deg[0..N) -> row_start ---------------------
// 1 block, 1024 threads (16 waves), 8 elems/thread/chunk, LDS cross-wave scan.
__global__ __launch_bounds__(1024) void k_scan_all(const int* __restrict__ deg,
                                                   int* __restrict__ row_start, int N) {
    __shared__ int wsum[16], wpre[16];
    int tid = threadIdx.x, lane = tid & 63, wv = tid >> 6;
    int run = 0;
    for (int base = 0; base < N; base += 8192) {
        int idx = base + tid * 8;
        int v[8]; int lsum = 0;
#pragma unroll
        for (int i = 0; i < 8; ++i) { v[i] = (idx + i < N) ? deg[idx + i] : 0; lsum += v[i]; }
        int pre = lsum;
#pragma unroll
        for (int off = 1; off < 64; off <<= 1) {
            int t = __shfl_up(pre, off, 64);
            if (lane >= off) pre += t;
        }
        if (lane == 63) wsum[wv] = pre;       // wave total (inclusive of all 64 lanes)
        __syncthreads();
        if (tid < 16) {
            int s = wsum[tid];
            int p = s;
#pragma unroll
            for (int off = 1; off < 16; off <<= 1) {
                int t = __shfl_up(p, off, 64);
                if (tid >= off) p += t;
            }
            wpre[tid] = p - s;                // exclusive prefix of wave totals
        }
        __syncthreads();
        int excl = run + wpre[wv] + (pre - lsum);
#pragma unroll
        for (int i = 0; i < 8; ++i) {
            if (idx + i < N) row_start[idx + i] = excl;
            excl += v[i];
        }
        run += wpre[15] + wsum[15];
        __syncthreads();                      // guard wsum reuse next chunk
    }
}

// ---------------- fused: atomic-free CSR scatter | weight prep -----------------------------
// Blocks [0, SB): csr[row_start[dst]+pos_e] = {src, e}
// Blocks [SB, SB+192): 768 waves of weight prep (fp32 [256][256] -> MFMA B-frag bf16 plane)
__global__ __launch_bounds__(256) void k_scatter_wprep(const int* __restrict__ src,
                                                       const int* __restrict__ dst,
                                                       const int* __restrict__ pos_e,
                                                       const int* __restrict__ row_start,
                                                       int2* __restrict__ csr, int E, int SB,
                                                       const float* __restrict__ W1l, ushort_t* WF1l,
                                                       const float* __restrict__ W1r, ushort_t* WF1r,
                                                       const float* __restrict__ W2l, ushort_t* WF2l,
                                                       const float* __restrict__ W2r, ushort_t* WF2r,
                                                       const float* __restrict__ Wm1, ushort_t* WFm) {
    int b = blockIdx.x;
    if (b < SB) {
        int e = b * 256 + threadIdx.x;
        if (e < E) {
            int pos = row_start[dst[e]] + pos_e[e];
            csr[pos] = make_int2(src[e], e);
        }
    } else {
        int wid = (b - SB) * 4 + (threadIdx.x >> 6);   // 0..767
        int lane = threadIdx.x & 63;
        int m = wid >> 7;       // 0..5
        int bb = wid & 127;
        const float* Wsrc; ushort_t* WF; int nbTot, nb0;
        if (m == 0)      { Wsrc = W1l; WF = WF1l; nbTot = 16; nb0 = 0; }
        else if (m == 1) { Wsrc = W1r; WF = WF1r; nbTot = 16; nb0 = 0; }
        else if (m == 2) { Wsrc = W2l; WF = WF2l; nbTot = 16; nb0 = 0; }
        else if (m == 3) { Wsrc = W2r; WF = WF2r; nbTot = 16; nb0 = 0; }
        else if (m == 4) { Wsrc = Wm1; WF = WFm;  nbTot = 32; nb0 = 0; }
        else             { Wsrc = Wm1 + (size_t)256 * 256; WF = WFm; nbTot = 32; nb0 = 16; }
        int kb = bb >> 4, nbL = bb & 15;
        int k = kb * 32 + (lane >> 4) * 8;
        int n = nbL * 16 + (lane & 15);
        size_t dstb = (size_t)(kb * nbTot + nb0 + nbL) * 512 + lane * 8;
#pragma unroll
        for (int j = 0; j < 8; ++j) {
            WF[dstb + j] = f2b(Wsrc[(size_t)(k + j) * 256 + n]);
        }
    }
}

// ---------------- fused SAGEConv layer: gather-aggregate -> LDS, dual MFMA GEMM, relu ------
// Block = 512 threads (8 waves), 64 nodes/block.
// Phase B (first, latency-hidden): stage the block's own 64 X rows into LDS As[1].
// Phase A: each wave mean-aggregates 8 nodes' neighbor rows into LDS As[0] (bf16).
// Phase C: h = relu(agg @ WFl + X @ WFr + bias).
// FUSE=0: write h to C.   FUSE=1 (conv2): restage h (bf16) into As[0] and run the
// P|Q GEMM (h @ WFm2, 512 cols) in-block, writing Pout/Qout directly.
template<int FUSE>
__global__ __launch_bounds__(512, 4) void k_conv(const ushort_t* __restrict__ X,
                                                 const int2* __restrict__ csr,
                                                 const int* __restrict__ row_start,
                                                 const int* __restrict__ deg,
                                                 const ushort_t* __restrict__ WFl,
                                                 const ushort_t* __restrict__ WFr,
                                                 const float* __restrict__ bias,
                                                 int M,
                                                 ushort_t* __restrict__ C,
                                                 const ushort_t* __restrict__ WFm2,
                                                 ushort_t* __restrict__ Pout,
                                                 ushort_t* __restrict__ Qout) {
    __shared__ ushort_t As[2][64 * PADW];   // 67.6 KB
    const int tid = threadIdx.x;
    const int lane = tid & 63;
    const int w = tid >> 6;              // 0..7
    const int quad = lane >> 4, l16 = lane & 15;
    const int m0 = blockIdx.x * 64;

    // ---- Phase B first: stage own X rows into As[1] (loads issued before the gather) ----
#pragma unroll
    for (int i = 0; i < 4; ++i) {
        int c = i * 512 + tid;
        int row = c >> 5, col = c & 31;
        int arow = m0 + row; if (arow >= M) arow = M - 1;
        *(uint4*)&As[1][row * PADW + col * 8] =
            *(const uint4*)(X + (size_t)arow * 256 + col * 8);
    }

    // ---- Phase A: gather-aggregate 8 nodes per wave into As[0] ----
    for (int t = 0; t < 8; ++t) {
        int node = m0 + w * 8 + t;               // wave-uniform
        if (node >= M) continue;
        int start = row_start[node];
        int cnt = deg[node];
        const int2* sp = csr + start;
        float acc[16] = {};
        for (int b = 0; b < cnt; b += 64) {
            int nb = min(64, cnt - b);
            int sidx = (lane < nb) ? sp[b + lane].x : 0;

            int jA = (quad < nb) ? quad : 0;
            int jB = (4 + quad < nb) ? 4 + quad : 0;
            int sA = __shfl(sidx, jA, 64);
            int sB = __shfl(sidx, jB, 64);
            const ushort_t* rA = X + (size_t)sA * HID + l16 * 16;
            const ushort_t* rB = X + (size_t)sB * HID + l16 * 16;
            short8 a0 = *(const short8*)(rA);
            short8 a1 = *(const short8*)(rA + 8);
            short8 b0 = *(const short8*)(rB);
            short8 b1 = *(const short8*)(rB + 8);

            for (int j8 = 0; j8 < nb; j8 += 8) {
                bool vA = (j8 + quad) < nb, vB = (j8 + 4 + quad) < nb;
                short8 na0 = a0, na1 = a1, nb0 = b0, nb1 = b1;
                int j1 = j8 + 8;
                if (j1 < nb) {
                    int cA = (j1 + quad < nb) ? j1 + quad : 0;
                    int cB = (j1 + 4 + quad < nb) ? j1 + 4 + quad : 0;
                    int zA = __shfl(sidx, cA, 64);
                    int zB = __shfl(sidx, cB, 64);
                    const ushort_t* qA = X + (size_t)zA * HID + l16 * 16;
                    const ushort_t* qB = X + (size_t)zB * HID + l16 * 16;
                    na0 = *(const short8*)(qA);
                    na1 = *(const short8*)(qA + 8);
                    nb0 = *(const short8*)(qB);
                    nb1 = *(const short8*)(qB + 8);
                }
                if (vA) {
#pragma unroll
                    for (int i = 0; i < 8; ++i) {
                        acc[i]     += b2f((ushort_t)a0[i]);
                        acc[8 + i] += b2f((ushort_t)a1[i]);
                    }
                }
                if (vB) {
#pragma unroll
                    for (int i = 0; i < 8; ++i) {
                        acc[i]     += b2f((ushort_t)b0[i]);
                        acc[8 + i] += b2f((ushort_t)b1[i]);
                    }
                }
                a0 = na0; a1 = na1; b0 = nb0; b1 = nb1;
            }
        }
#pragma unroll
        for (int i = 0; i < 16; ++i) {
            acc[i] += __shfl_down(acc[i], 32, 64);
            acc[i] += __shfl_down(acc[i], 16, 64);
        }
        if (quad == 0) {
            float sc = 1.0f / (float)max(cnt, 1);
            short8 o0, o1;
#pragma unroll
            for (int i = 0; i < 8; ++i) {
                o0[i] = (short)f2b(acc[i] * sc);
                o1[i] = (short)f2b(acc[8 + i] * sc);
            }
            ushort_t* op = &As[0][(w * 8 + t) * PADW + l16 * 16];
            *(short8*)(op) = o0;
            *(short8*)(op + 8) = o1;
        }
    }
    __syncthreads();

    // ---- Phase C: dual GEMM ----
    const int wm = w >> 2, wn = w & 3;   // 2 M-halves x 4 N-strips of 64
    floatx4 acc[2][4] = {};
#pragma unroll
    for (int op = 0; op < 2; ++op) {
        const ushort_t* Ap = As[op];
        const ushort_t* WF = op ? WFr : WFl;
        const ushort_t* a0p = &Ap[(wm * 32 + l16) * PADW + quad * 8];
        const ushort_t* a1p = a0p + 16 * PADW;
        const ushort_t* wp = WF + (size_t)(wn * 4) * 512 + lane * 8;
#pragma unroll
        for (int kb = 0; kb < 8; ++kb) {
            short8 a0 = *(const short8*)(a0p + kb * 32);
            short8 a1 = *(const short8*)(a1p + kb * 32);
            const ushort_t* wkb = wp + (size_t)kb * 16 * 512;
#pragma unroll
            for (int nj = 0; nj < 4; ++nj) {
                short8 bj = *(const short8*)(wkb + nj * 512);
                acc[0][nj] = __builtin_amdgcn_mfma_f32_16x16x32_bf16(a0, bj, acc[0][nj], 0, 0, 0);
                acc[1][nj] = __builtin_amdgcn_mfma_f32_16x16x32_bf16(a1, bj, acc[1][nj], 0, 0, 0);
            }
        }
    }

    if constexpr (FUSE == 0) {
        // ---- epilogue: bias + relu -> C ----
#pragma unroll
        for (int mi = 0; mi < 2; ++mi) {
#pragma unroll
            for (int nj = 0; nj < 4; ++nj) {
                int col = wn * 64 + nj * 16 + l16;
                float b = bias[col];
                int rbase = m0 + wm * 32 + mi * 16 + quad * 4;
#pragma unroll
                for (int reg = 0; reg < 4; ++reg) {
                    int r = rbase + reg;
                    if (r >= M) continue;
                    float v = fmaxf(acc[mi][nj][reg] + b, 0.f);
                    C[(size_t)r * 256 + col] = f2b(v);
                }
            }
        }
    } else {
        // ---- restage h = relu(acc + bias) as bf16 into As[0] ----
        __syncthreads();   // all waves done reading As
#pragma unroll
        for (int mi = 0; mi < 2; ++mi) {
#pragma unroll
            for (int nj = 0; nj < 4; ++nj) {
                int col = wn * 64 + nj * 16 + l16;
                float b = bias[col];
                int rloc = wm * 32 + mi * 16 + quad * 4;
#pragma unroll
                for (int reg = 0; reg < 4; ++reg) {
                    float v = fmaxf(acc[mi][nj][reg] + b, 0.f);
                    As[0][(rloc + reg) * PADW + col] = f2b(v);
                }
            }
        }
        __syncthreads();

        // ---- second GEMM: h (64x256) @ WFm2 (256x512) -> P|Q ----
        floatx4 acc2[2][8] = {};
        const ushort_t* a0p = &As[0][(wm * 32 + l16) * PADW + quad * 8];
        const ushort_t* a1p = a0p + 16 * PADW;
        const ushort_t* wp = WFm2 + (size_t)(wn * 8) * 512 + lane * 8;
#pragma unroll
        for (int kb = 0; kb < 8; ++kb) {
            short8 a0 = *(const short8*)(a0p + kb * 32);
            short8 a1 = *(const short8*)(a1p + kb * 32);
            const ushort_t* wkb = wp + (size_t)kb * 32 * 512;
#pragma unroll
            for (int nj = 0; nj < 8; ++nj) {
                short8 bj = *(const short8*)(wkb + nj * 512);
                acc2[0][nj] = __builtin_amdgcn_mfma_f32_16x16x32_bf16(a0, bj, acc2[0][nj], 0, 0, 0);
                acc2[1][nj] = __builtin_amdgcn_mfma_f32_16x16x32_bf16(a1, bj, acc2[1][nj], 0, 0, 0);
            }
        }

        // ---- epilogue2: write P (cols 0..255) / Q (cols 256..511), no bias/relu ----
#pragma unroll
        for (int mi = 0; mi < 2; ++mi) {
#pragma unroll
            for (int nj = 0; nj < 8; ++nj) {
                int col = wn * 128 + nj * 16 + l16;
                ushort_t* dstp = (col < 256) ? Pout : Qout;
                int c = col & 255;
                int rbase = m0 + wm * 32 + mi * 16 + quad * 4;
#pragma unroll
                for (int reg = 0; reg < 4; ++reg) {
                    int r = rbase + reg;
                    if (r >= M) continue;
                    dstp[(size_t)r * 256 + c] = f2b(acc2[mi][nj][reg]);
                }
            }
        }
    }
}

// ---------------- edge MLP: persistent waves, software-pipelined ---------------------------
__global__ __launch_bounds__(256) void k_edge(const ushort_t* __restrict__ P,
                                              const ushort_t* __restrict__ Q,
                                              const int2* __restrict__ csr,
                                              const int* __restrict__ row_start,
                                              const int* __restrict__ deg,
                                              const float* __restrict__ bm1,
                                              const float* __restrict__ Wm2,
                                              const float* __restrict__ bm2,
                                              float* __restrict__ out, int N, int stride) {
    int lane = threadIdx.x & 63;
    int wid = blockIdx.x * 4 + (threadIdx.x >> 6);
    int half = lane >> 5, l32 = lane & 31;

    float w0[8], w1[8], bb[8];
    const float* bp = bm1 + l32 * 8;
    const float2* wp = (const float2*)Wm2 + l32 * 8;
#pragma unroll
    for (int i = 0; i < 8; ++i) {
        float2 wv = wp[i];
        w0[i] = wv.x; w1[i] = wv.y;
        bb[i] = bp[i];
    }
    float bo0 = bm2[0], bo1 = bm2[1];

    for (int node = wid; node < N; node += stride) {
        int start = row_start[node];
        int cnt = deg[node];
        if (cnt == 0) continue;

        short8 qv = *(const short8*)(Q + (size_t)node * HID + l32 * 8);
        float qb[8];
#pragma unroll
        for (int i = 0; i < 8; ++i) qb[i] = b2f((ushort_t)qv[i]) + bb[i];

        const int2* sp = csr + start;
        for (int b = 0; b < cnt; b += 64) {
            int nb = min(64, cnt - b);
            int2 se = (lane < nb) ? sp[b + lane] : make_int2(0, 0);

            int iA = (half < nb) ? half : 0;
            int iB = (2 + half < nb) ? 2 + half : 0;
            int iC = (4 + half < nb) ? 4 + half : 0;
            int iD = (6 + half < nb) ? 6 + half : 0;
            int sA = __shfl(se.x, iA, 64);
            int sB = __shfl(se.x, iB, 64);
            int sC = __shfl(se.x, iC, 64);
            int sD = __shfl(se.x, iD, 64);
            short8 pA = *(const short8*)(P + (size_t)sA * HID + l32 * 8);
            short8 pB = *(const short8*)(P + (size_t)sB * HID + l32 * 8);
            short8 pC = *(const short8*)(P + (size_t)sC * HID + l32 * 8);
            short8 pD = *(const short8*)(P + (size_t)sD * HID + l32 * 8);

            for (int j0 = 0; j0 < nb; j0 += 8) {
                bool vA = j0 + half < nb, vB = j0 + 2 + half < nb;
                bool vC = j0 + 4 + half < nb, vD = j0 + 6 + half < nb;

                int kA = iA, kB = iB, kC = iC, kD = iD;
                short8 nA = pA, nB = pB, nC = pC, nD = pD;
                int j1 = j0 + 8;
                if (j1 < nb) {
                    kA = (j1 + half < nb) ? j1 + half : 0;
                    kB = (j1 + 2 + half < nb) ? j1 + 2 + half : 0;
                    kC = (j1 + 4 + half < nb) ? j1 + 4 + half : 0;
                    kD = (j1 + 6 + half < nb) ? j1 + 6 + half : 0;
                    int zA = __shfl(se.x, kA, 64);
                    int zB = __shfl(se.x, kB, 64);
                    int zC = __shfl(se.x, kC, 64);
                    int zD = __shfl(se.x, kD, 64);
                    nA = *(const short8*)(P + (size_t)zA * HID + l32 * 8);
                    nB = *(const short8*)(P + (size_t)zB * HID + l32 * 8);
                    nC = *(const short8*)(P + (size_t)zC * HID + l32 * 8);
                    nD = *(const short8*)(P + (size_t)zD * HID + l32 * 8);
                }

                float aA0 = 0.f, aA1 = 0.f, aB0 = 0.f, aB1 = 0.f;
                float aC0 = 0.f, aC1 = 0.f, aD0 = 0.f, aD1 = 0.f;
#pragma unroll
                for (int i = 0; i < 8; ++i) {
                    float hA = fmaxf(b2f((ushort_t)pA[i]) + qb[i], 0.f);
                    float hB = fmaxf(b2f((ushort_t)pB[i]) + qb[i], 0.f);
                    float hC = fmaxf(b2f((ushort_t)pC[i]) + qb[i], 0.f);
                    float hD = fmaxf(b2f((ushort_t)pD[i]) + qb[i], 0.f);
                    aA0 += hA * w0[i]; aA1 += hA * w1[i];
                    aB0 += hB * w0[i]; aB1 += hB * w1[i];
                    aC0 += hC * w0[i]; aC1 += hC * w1[i];
                    aD0 += hD * w0[i]; aD1 += hD * w1[i];
                }
#pragma unroll
                for (int off = 16; off > 0; off >>= 1) {
                    aA0 += __shfl_down(aA0, off, 32);
                    aA1 += __shfl_down(aA1, off, 32);
                    aB0 += __shfl_down(aB0, off, 32);
                    aB1 += __shfl_down(aB1, off, 32);
                    aC0 += __shfl_down(aC0, off, 32);
                    aC1 += __shfl_down(aC1, off, 32);
                    aD0 += __shfl_down(aD0, off, 32);
                    aD1 += __shfl_down(aD1, off, 32);
                }
                int eA = __shfl(se.y, iA, 64);
                int eB = __shfl(se.y, iB, 64);
                int eC = __shfl(se.y, iC, 64);
                int eD = __shfl(se.y, iD, 64);
                if (l32 == 0) {
                    if (vA) { float2 o; o.x = aA0 + bo0; o.y = aA1 + bo1; ((float2*)out)[eA] = o; }
                    if (vB) { float2 o; o.x = aB0 + bo0; o.y = aB1 + bo1; ((float2*)out)[eB] = o; }
                    if (vC) { float2 o; o.x = aC0 + bo0; o.y = aC1 + bo1; ((float2*)out)[eC] = o; }
                    if (vD) { float2 o; o.x = aD0 + bo0; o.y = aD1 + bo1; ((float2*)out)[eD] = o; }
                }
                pA = nA; pB = nB; pC = nC; pD = nD;
                iA = kA; iB = kB; iC = kC; iD = kD;
            }
        }
    }
}

extern "C" void kernel_launch(void* const* d_in, const int* in_sizes, int n_in,
                              void* d_out, int out_size, void* d_ws, size_t ws_size,
                              hipStream_t stream) {
    const float* x   = (const float*)d_in[0];
    const int*   ei  = (const int*)d_in[1];
    const float* W1l = (const float*)d_in[2];
    const float* b1l = (const float*)d_in[3];
    const float* W1r = (const float*)d_in[4];
    const float* W2l = (const float*)d_in[5];
    const float* b2l = (const float*)d_in[6];
    const float* W2r = (const float*)d_in[7];
    const float* Wm1 = (const float*)d_in[8];
    const float* bm1 = (const float*)d_in[9];
    const float* Wm2 = (const float*)d_in[10];
    const float* bm2 = (const float*)d_in[11];

    const int N = in_sizes[0] / IN_DIM;   // 50000
    const int E = in_sizes[1] / 2;        // 800000
    const int* src = ei;
    const int* dst = ei + E;

    // ---- workspace ----
    char* ws = (char*)d_ws;
    size_t off = 0;
    auto alloc = [&](size_t bytes) { void* p = ws + off; off = (off + bytes + 255) & ~(size_t)255; return p; };
    int* deg       = (int*)alloc((size_t)N * 4);
    int* row_start = (int*)alloc((size_t)N * 4);
    int* pos_e     = (int*)alloc((size_t)E * 4);
    int2* csr      = (int2*)alloc((size_t)E * 8);
    size_t matB = (size_t)N * HID * sizeof(ushort_t);          // 25.6 MB
    ushort_t* xb   = (ushort_t*)alloc(matB);
    ushort_t* h1b  = (ushort_t*)alloc(matB);
    ushort_t* Pb   = (ushort_t*)alloc(matB);
    ushort_t* Qb   = (ushort_t*)alloc(matB);
    size_t wfB  = (size_t)8 * 16 * 512 * sizeof(ushort_t);      // 128 KB (single plane)
    ushort_t* WF1l = (ushort_t*)alloc(wfB);
    ushort_t* WF1r = (ushort_t*)alloc(wfB);
    ushort_t* WF2l = (ushort_t*)alloc(wfB);
    ushort_t* WF2r = (ushort_t*)alloc(wfB);
    ushort_t* WFm  = (ushort_t*)alloc(wfB * 2);                 // nbTot=32
    float* out = (float*)d_out;

    int mrows = (N + 63) / 64;
    const int CB = (E + 255) / 256;           // count blocks
    const int XB = (N * HID / 4 + 255) / 256; // cast blocks
    const int SB = (E + 255) / 256;           // scatter blocks

    // ---- CSR build + cast + weight prep (fused, 4 launches total) ----
    hipMemsetAsync(deg, 0, (size_t)N * 4, stream);
    k_count_cast<<<CB + XB, 256, 0, stream>>>(dst, deg, pos_e, E, CB, x, xb, N * HID / 4);
    k_scan_all<<<1, 1024, 0, stream>>>(deg, row_start, N);
    k_scatter_wprep<<<SB + 192, 256, 0, stream>>>(src, dst, pos_e, row_start, csr, E, SB,
                                                  W1l, WF1l, W1r, WF1r, W2l, WF2l, W2r, WF2r,
                                                  Wm1, WFm);

    // ---- conv1 (fused gather + dual GEMM) ----
    k_conv<0><<<mrows, 512, 0, stream>>>(xb, csr, row_start, deg, WF1l, WF1r, b1l, N, h1b,
                                         nullptr, nullptr, nullptr);

    // ---- conv2 + P|Q GEMM fused ----
    k_conv<1><<<mrows, 512, 0, stream>>>(h1b, csr, row_start, deg, WF2l, WF2r, b2l, N, nullptr,
                                         WFm, Pb, Qb);

    // ---- edge MLP (persistent waves) ----
    const int EB = 2048;                  // 8 blocks/CU
    k_edge<<<EB, 256, 0, stream>>>(Pb, Qb, csr, row_start, deg, bm1, Wm2, bm2, out, N, EB * 4);
}

// Round 8
// 453.587 us; speedup vs baseline: 1.0818x; 1.0818x over previous
//
#include <hip/hip_runtime.h>

#define IN_DIM 256
#define HID 256
#define SCAN_CHUNK 512
#define PADW 264   // 256 + 16 ushort pad

typedef unsigned short ushort_t;
typedef __attribute__((ext_vector_type(8))) short short8;
typedef __attribute__((ext_vector_type(4))) float floatx4;

__device__ __forceinline__ float b2f(ushort_t h) {
    union { unsigned int u; float f; } c; c.u = ((unsigned int)h) << 16; return c.f;
}
__device__ __forceinline__ ushort_t f2b(float f) {  // round-to-nearest-even
    union { float f; unsigned int u; } c; c.f = f;
    unsigned int u = c.u;
    unsigned int r = (u + 0x7fffu + ((u >> 16) & 1u)) >> 16;
    return (ushort_t)r;
}

// ---------------- degree + per-edge slot (single atomic pass) ----------------
__global__ void k_count_pos(const int* __restrict__ dst, int* __restrict__ deg,
                            int* __restrict__ pos_e, int E) {
    int e = blockIdx.x * blockDim.x + threadIdx.x;
    if (e < E) pos_e[e] = atomicAdd(&deg[dst[e]], 1);
}

// ---------------- scan (3-kernel parallel version — proven faster than 1-block) ------------
__global__ __launch_bounds__(64) void k_chunk_sum(const int* __restrict__ deg,
                                                  int* __restrict__ partials, int N) {
    int lane = threadIdx.x;
    int base = blockIdx.x * SCAN_CHUNK + lane * 8;
    int s = 0;
#pragma unroll
    for (int i = 0; i < 8; ++i) s += (base + i < N) ? deg[base + i] : 0;
#pragma unroll
    for (int off = 32; off > 0; off >>= 1) s += __shfl_down(s, off, 64);
    if (lane == 0) partials[blockIdx.x] = s;
}

__global__ __launch_bounds__(64) void k_scan_partials(int* __restrict__ partials, int nb) {
    int lane = threadIdx.x;
    int run = 0;
    for (int base = 0; base < nb; base += 64) {
        int v = (base + lane < nb) ? partials[base + lane] : 0;
        int s = v;
#pragma unroll
        for (int off = 1; off < 64; off <<= 1) {
            int t = __shfl_up(s, off, 64);
            if (lane >= off) s += t;
        }
        if (base + lane < nb) partials[base + lane] = run + s - v;
        run += __shfl(s, 63, 64);
    }
}

__global__ __launch_bounds__(64) void k_scan_chunks(const int* __restrict__ deg,
                                                    const int* __restrict__ partials,
                                                    int* __restrict__ row_start, int N) {
    int lane = threadIdx.x;
    int base = blockIdx.x * SCAN_CHUNK + lane * 8;
    int v[8]; int lsum = 0;
#pragma unroll
    for (int i = 0; i < 8; ++i) { v[i] = (base + i < N) ? deg[base + i] : 0; lsum += v[i]; }
    int pre = lsum;
#pragma unroll
    for (int off = 1; off < 64; off <<= 1) {
        int t = __shfl_up(pre, off, 64);
        if (lane >= off) pre += t;
    }
    pre -= lsum;
    int run = partials[blockIdx.x] + pre;
#pragma unroll
    for (int i = 0; i < 8; ++i) {
        if (base + i < N) row_start[base + i] = run;
        run += v[i];
    }
}

// ---------------- cast x -> bf16 ----------------
__global__ __launch_bounds__(256) void k_cast(const float* __restrict__ x,
                                              ushort_t* __restrict__ xb, int n4) {
    int i = blockIdx.x * blockDim.x + threadIdx.x;
    if (i >= n4) return;
    float4 v = ((const float4*)x)[i];
    ushort4 o;
    o.x = f2b(v.x); o.y = f2b(v.y); o.z = f2b(v.z); o.w = f2b(v.w);
    ((ushort4*)xb)[i] = o;
}

// ---------------- fused: atomic-free CSR scatter | weight prep -----------------------------
// Both halves are embarrassingly parallel with disjoint resources (scatter: write-allocate
// bound; wprep: tiny streaming) — safe fusion, saves one launch gap.
__global__ __launch_bounds__(256) void k_scatter_wprep(const int* __restrict__ src,
                                                       const int* __restrict__ dst,
                                                       const int* __restrict__ pos_e,
                                                       const int* __restrict__ row_start,
                                                       int2* __restrict__ csr, int E, int SB,
                                                       const float* __restrict__ W1l, ushort_t* WF1l,
                                                       const float* __restrict__ W1r, ushort_t* WF1r,
                                                       const float* __restrict__ W2l, ushort_t* WF2l,
                                                       const float* __restrict__ W2r, ushort_t* WF2r,
                                                       const float* __restrict__ Wm1, ushort_t* WFm) {
    int b = blockIdx.x;
    if (b < SB) {
        int e = b * 256 + threadIdx.x;
        if (e < E) {
            int pos = row_start[dst[e]] + pos_e[e];
            csr[pos] = make_int2(src[e], e);
        }
    } else {
        int wid = (b - SB) * 4 + (threadIdx.x >> 6);   // 0..767
        int lane = threadIdx.x & 63;
        int m = wid >> 7;       // 0..5
        int bb = wid & 127;
        const float* Wsrc; ushort_t* WF; int nbTot, nb0;
        if (m == 0)      { Wsrc = W1l; WF = WF1l; nbTot = 16; nb0 = 0; }
        else if (m == 1) { Wsrc = W1r; WF = WF1r; nbTot = 16; nb0 = 0; }
        else if (m == 2) { Wsrc = W2l; WF = WF2l; nbTot = 16; nb0 = 0; }
        else if (m == 3) { Wsrc = W2r; WF = WF2r; nbTot = 16; nb0 = 0; }
        else if (m == 4) { Wsrc = Wm1; WF = WFm;  nbTot = 32; nb0 = 0; }
        else             { Wsrc = Wm1 + (size_t)256 * 256; WF = WFm; nbTot = 32; nb0 = 16; }
        int kb = bb >> 4, nbL = bb & 15;
        int k = kb * 32 + (lane >> 4) * 8;
        int n = nbL * 16 + (lane & 15);
        size_t dstb = (size_t)(kb * nbTot + nb0 + nbL) * 512 + lane * 8;
#pragma unroll
        for (int j = 0; j < 8; ++j) {
            WF[dstb + j] = f2b(Wsrc[(size_t)(k + j) * 256 + n]);
        }
    }
}

// ---------------- fused SAGEConv layer: gather-aggregate -> LDS, dual MFMA GEMM, relu ------
// Block = 512 threads (8 waves), 64 nodes/block.
// Phase B (first, latency-hidden): stage the block's own 64 X rows into LDS As[1].
// Phase A: each wave mean-aggregates 8 nodes' neighbor rows into LDS As[0] (bf16).
// Phase C: h = relu(agg @ WFl + X @ WFr + bias).
// FUSE=0: write h to C.   FUSE=1 (conv2): restage h (bf16) into As[0] and run the
// P|Q GEMM (h @ WFm2, 512 cols) in-block, writing Pout/Qout directly.
template<int FUSE>
__global__ __launch_bounds__(512, 4) void k_conv(const ushort_t* __restrict__ X,
                                                 const int2* __restrict__ csr,
                                                 const int* __restrict__ row_start,
                                                 const int* __restrict__ deg,
                                                 const ushort_t* __restrict__ WFl,
                                                 const ushort_t* __restrict__ WFr,
                                                 const float* __restrict__ bias,
                                                 int M,
                                                 ushort_t* __restrict__ C,
                                                 const ushort_t* __restrict__ WFm2,
                                                 ushort_t* __restrict__ Pout,
                                                 ushort_t* __restrict__ Qout) {
    __shared__ ushort_t As[2][64 * PADW];   // 67.6 KB
    const int tid = threadIdx.x;
    const int lane = tid & 63;
    const int w = tid >> 6;              // 0..7
    const int quad = lane >> 4, l16 = lane & 15;
    const int m0 = blockIdx.x * 64;

    // ---- Phase B first: stage own X rows into As[1] (loads issued before the gather) ----
#pragma unroll
    for (int i = 0; i < 4; ++i) {
        int c = i * 512 + tid;
        int row = c >> 5, col = c & 31;
        int arow = m0 + row; if (arow >= M) arow = M - 1;
        *(uint4*)&As[1][row * PADW + col * 8] =
            *(const uint4*)(X + (size_t)arow * 256 + col * 8);
    }

    // ---- Phase A: gather-aggregate 8 nodes per wave into As[0] ----
    for (int t = 0; t < 8; ++t) {
        int node = m0 + w * 8 + t;               // wave-uniform
        if (node >= M) continue;
        int start = row_start[node];
        int cnt = deg[node];
        const int2* sp = csr + start;
        float acc[16] = {};
        for (int b = 0; b < cnt; b += 64) {
            int nb = min(64, cnt - b);
            int sidx = (lane < nb) ? sp[b + lane].x : 0;

            int jA = (quad < nb) ? quad : 0;
            int jB = (4 + quad < nb) ? 4 + quad : 0;
            int sA = __shfl(sidx, jA, 64);
            int sB = __shfl(sidx, jB, 64);
            const ushort_t* rA = X + (size_t)sA * HID + l16 * 16;
            const ushort_t* rB = X + (size_t)sB * HID + l16 * 16;
            short8 a0 = *(const short8*)(rA);
            short8 a1 = *(const short8*)(rA + 8);
            short8 b0 = *(const short8*)(rB);
            short8 b1 = *(const short8*)(rB + 8);

            for (int j8 = 0; j8 < nb; j8 += 8) {
                bool vA = (j8 + quad) < nb, vB = (j8 + 4 + quad) < nb;
                short8 na0 = a0, na1 = a1, nb0 = b0, nb1 = b1;
                int j1 = j8 + 8;
                if (j1 < nb) {
                    int cA = (j1 + quad < nb) ? j1 + quad : 0;
                    int cB = (j1 + 4 + quad < nb) ? j1 + 4 + quad : 0;
                    int zA = __shfl(sidx, cA, 64);
                    int zB = __shfl(sidx, cB, 64);
                    const ushort_t* qA = X + (size_t)zA * HID + l16 * 16;
                    const ushort_t* qB = X + (size_t)zB * HID + l16 * 16;
                    na0 = *(const short8*)(qA);
                    na1 = *(const short8*)(qA + 8);
                    nb0 = *(const short8*)(qB);
                    nb1 = *(const short8*)(qB + 8);
                }
                if (vA) {
#pragma unroll
                    for (int i = 0; i < 8; ++i) {
                        acc[i]     += b2f((ushort_t)a0[i]);
                        acc[8 + i] += b2f((ushort_t)a1[i]);
                    }
                }
                if (vB) {
#pragma unroll
                    for (int i = 0; i < 8; ++i) {
                        acc[i]     += b2f((ushort_t)b0[i]);
                        acc[8 + i] += b2f((ushort_t)b1[i]);
                    }
                }
                a0 = na0; a1 = na1; b0 = nb0; b1 = nb1;
            }
        }
#pragma unroll
        for (int i = 0; i < 16; ++i) {
            acc[i] += __shfl_down(acc[i], 32, 64);
            acc[i] += __shfl_down(acc[i], 16, 64);
        }
        if (quad == 0) {
            float sc = 1.0f / (float)max(cnt, 1);
            short8 o0, o1;
#pragma unroll
            for (int i = 0; i < 8; ++i) {
                o0[i] = (short)f2b(acc[i] * sc);
                o1[i] = (short)f2b(acc[8 + i] * sc);
            }
            ushort_t* op = &As[0][(w * 8 + t) * PADW + l16 * 16];
            *(short8*)(op) = o0;
            *(short8*)(op + 8) = o1;
        }
    }
    __syncthreads();

    // ---- Phase C: dual GEMM ----
    const int wm = w >> 2, wn = w & 3;   // 2 M-halves x 4 N-strips of 64
    floatx4 acc[2][4] = {};
#pragma unroll
    for (int op = 0; op < 2; ++op) {
        const ushort_t* Ap = As[op];
        const ushort_t* WF = op ? WFr : WFl;
        const ushort_t* a0p = &Ap[(wm * 32 + l16) * PADW + quad * 8];
        const ushort_t* a1p = a0p + 16 * PADW;
        const ushort_t* wp = WF + (size_t)(wn * 4) * 512 + lane * 8;
#pragma unroll
        for (int kb = 0; kb < 8; ++kb) {
            short8 a0 = *(const short8*)(a0p + kb * 32);
            short8 a1 = *(const short8*)(a1p + kb * 32);
            const ushort_t* wkb = wp + (size_t)kb * 16 * 512;
#pragma unroll
            for (int nj = 0; nj < 4; ++nj) {
                short8 bj = *(const short8*)(wkb + nj * 512);
                acc[0][nj] = __builtin_amdgcn_mfma_f32_16x16x32_bf16(a0, bj, acc[0][nj], 0, 0, 0);
                acc[1][nj] = __builtin_amdgcn_mfma_f32_16x16x32_bf16(a1, bj, acc[1][nj], 0, 0, 0);
            }
        }
    }

    if constexpr (FUSE == 0) {
        // ---- epilogue: bias + relu -> C ----
#pragma unroll
        for (int mi = 0; mi < 2; ++mi) {
#pragma unroll
            for (int nj = 0; nj < 4; ++nj) {
                int col = wn * 64 + nj * 16 + l16;
                float b = bias[col];
                int rbase = m0 + wm * 32 + mi * 16 + quad * 4;
#pragma unroll
                for (int reg = 0; reg < 4; ++reg) {
                    int r = rbase + reg;
                    if (r >= M) continue;
                    float v = fmaxf(acc[mi][nj][reg] + b, 0.f);
                    C[(size_t)r * 256 + col] = f2b(v);
                }
            }
        }
    } else {
        // ---- restage h = relu(acc + bias) as bf16 into As[0] ----
        __syncthreads();   // all waves done reading As
#pragma unroll
        for (int mi = 0; mi < 2; ++mi) {
#pragma unroll
            for (int nj = 0; nj < 4; ++nj) {
                int col = wn * 64 + nj * 16 + l16;
                float b = bias[col];
                int rloc = wm * 32 + mi * 16 + quad * 4;
#pragma unroll
                for (int reg = 0; reg < 4; ++reg) {
                    float v = fmaxf(acc[mi][nj][reg] + b, 0.f);
                    As[0][(rloc + reg) * PADW + col] = f2b(v);
                }
            }
        }
        __syncthreads();

        // ---- second GEMM: h (64x256) @ WFm2 (256x512) -> P|Q ----
        floatx4 acc2[2][8] = {};
        const ushort_t* a0p = &As[0][(wm * 32 + l16) * PADW + quad * 8];
        const ushort_t* a1p = a0p + 16 * PADW;
        const ushort_t* wp = WFm2 + (size_t)(wn * 8) * 512 + lane * 8;
#pragma unroll
        for (int kb = 0; kb < 8; ++kb) {
            short8 a0 = *(const short8*)(a0p + kb * 32);
            short8 a1 = *(const short8*)(a1p + kb * 32);
            const ushort_t* wkb = wp + (size_t)kb * 32 * 512;
#pragma unroll
            for (int nj = 0; nj < 8; ++nj) {
                short8 bj = *(const short8*)(wkb + nj * 512);
                acc2[0][nj] = __builtin_amdgcn_mfma_f32_16x16x32_bf16(a0, bj, acc2[0][nj], 0, 0, 0);
                acc2[1][nj] = __builtin_amdgcn_mfma_f32_16x16x32_bf16(a1, bj, acc2[1][nj], 0, 0, 0);
            }
        }

        // ---- epilogue2: write P (cols 0..255) / Q (cols 256..511), no bias/relu ----
#pragma unroll
        for (int mi = 0; mi < 2; ++mi) {
#pragma unroll
            for (int nj = 0; nj < 8; ++nj) {
                int col = wn * 128 + nj * 16 + l16;
                ushort_t* dstp = (col < 256) ? Pout : Qout;
                int c = col & 255;
                int rbase = m0 + wm * 32 + mi * 16 + quad * 4;
#pragma unroll
                for (int reg = 0; reg < 4; ++reg) {
                    int r = rbase + reg;
                    if (r >= M) continue;
                    dstp[(size_t)r * 256 + c] = f2b(acc2[mi][nj][reg]);
                }
            }
        }
    }
}

// ---------------- edge MLP: persistent waves, software-pipelined ---------------------------
__global__ __launch_bounds__(256) void k_edge(const ushort_t* __restrict__ P,
                                              const ushort_t* __restrict__ Q,
                                              const int2* __restrict__ csr,
                                              const int* __restrict__ row_start,
                                              const int* __restrict__ deg,
                                              const float* __restrict__ bm1,
                                              const float* __restrict__ Wm2,
                                              const float* __restrict__ bm2,
                                              float* __restrict__ out, int N, int stride) {
    int lane = threadIdx.x & 63;
    int wid = blockIdx.x * 4 + (threadIdx.x >> 6);
    int half = lane >> 5, l32 = lane & 31;

    float w0[8], w1[8], bb[8];
    const float* bp = bm1 + l32 * 8;
    const float2* wp = (const float2*)Wm2 + l32 * 8;
#pragma unroll
    for (int i = 0; i < 8; ++i) {
        float2 wv = wp[i];
        w0[i] = wv.x; w1[i] = wv.y;
        bb[i] = bp[i];
    }
    float bo0 = bm2[0], bo1 = bm2[1];

    for (int node = wid; node < N; node += stride) {
        int start = row_start[node];
        int cnt = deg[node];
        if (cnt == 0) continue;

        short8 qv = *(const short8*)(Q + (size_t)node * HID + l32 * 8);
        float qb[8];
#pragma unroll
        for (int i = 0; i < 8; ++i) qb[i] = b2f((ushort_t)qv[i]) + bb[i];

        const int2* sp = csr + start;
        for (int b = 0; b < cnt; b += 64) {
            int nb = min(64, cnt - b);
            int2 se = (lane < nb) ? sp[b + lane] : make_int2(0, 0);

            int iA = (half < nb) ? half : 0;
            int iB = (2 + half < nb) ? 2 + half : 0;
            int iC = (4 + half < nb) ? 4 + half : 0;
            int iD = (6 + half < nb) ? 6 + half : 0;
            int sA = __shfl(se.x, iA, 64);
            int sB = __shfl(se.x, iB, 64);
            int sC = __shfl(se.x, iC, 64);
            int sD = __shfl(se.x, iD, 64);
            short8 pA = *(const short8*)(P + (size_t)sA * HID + l32 * 8);
            short8 pB = *(const short8*)(P + (size_t)sB * HID + l32 * 8);
            short8 pC = *(const short8*)(P + (size_t)sC * HID + l32 * 8);
            short8 pD = *(const short8*)(P + (size_t)sD * HID + l32 * 8);

            for (int j0 = 0; j0 < nb; j0 += 8) {
                bool vA = j0 + half < nb, vB = j0 + 2 + half < nb;
                bool vC = j0 + 4 + half < nb, vD = j0 + 6 + half < nb;

                int kA = iA, kB = iB, kC = iC, kD = iD;
                short8 nA = pA, nB = pB, nC = pC, nD = pD;
                int j1 = j0 + 8;
                if (j1 < nb) {
                    kA = (j1 + half < nb) ? j1 + half : 0;
                    kB = (j1 + 2 + half < nb) ? j1 + 2 + half : 0;
                    kC = (j1 + 4 + half < nb) ? j1 + 4 + half : 0;
                    kD = (j1 + 6 + half < nb) ? j1 + 6 + half : 0;
                    int zA = __shfl(se.x, kA, 64);
                    int zB = __shfl(se.x, kB, 64);
                    int zC = __shfl(se.x, kC, 64);
                    int zD = __shfl(se.x, kD, 64);
                    nA = *(const short8*)(P + (size_t)zA * HID + l32 * 8);
                    nB = *(const short8*)(P + (size_t)zB * HID + l32 * 8);
                    nC = *(const short8*)(P + (size_t)zC * HID + l32 * 8);
                    nD = *(const short8*)(P + (size_t)zD * HID + l32 * 8);
                }

                float aA0 = 0.f, aA1 = 0.f, aB0 = 0.f, aB1 = 0.f;
                float aC0 = 0.f, aC1 = 0.f, aD0 = 0.f, aD1 = 0.f;
#pragma unroll
                for (int i = 0; i < 8; ++i) {
                    float hA = fmaxf(b2f((ushort_t)pA[i]) + qb[i], 0.f);
                    float hB = fmaxf(b2f((ushort_t)pB[i]) + qb[i], 0.f);
                    float hC = fmaxf(b2f((ushort_t)pC[i]) + qb[i], 0.f);
                    float hD = fmaxf(b2f((ushort_t)pD[i]) + qb[i], 0.f);
                    aA0 += hA * w0[i]; aA1 += hA * w1[i];
                    aB0 += hB * w0[i]; aB1 += hB * w1[i];
                    aC0 += hC * w0[i]; aC1 += hC * w1[i];
                    aD0 += hD * w0[i]; aD1 += hD * w1[i];
                }
#pragma unroll
                for (int off = 16; off > 0; off >>= 1) {
                    aA0 += __shfl_down(aA0, off, 32);
                    aA1 += __shfl_down(aA1, off, 32);
                    aB0 += __shfl_down(aB0, off, 32);
                    aB1 += __shfl_down(aB1, off, 32);
                    aC0 += __shfl_down(aC0, off, 32);
                    aC1 += __shfl_down(aC1, off, 32);
                    aD0 += __shfl_down(aD0, off, 32);
                    aD1 += __shfl_down(aD1, off, 32);
                }
                int eA = __shfl(se.y, iA, 64);
                int eB = __shfl(se.y, iB, 64);
                int eC = __shfl(se.y, iC, 64);
                int eD = __shfl(se.y, iD, 64);
                if (l32 == 0) {
                    if (vA) { float2 o; o.x = aA0 + bo0; o.y = aA1 + bo1; ((float2*)out)[eA] = o; }
                    if (vB) { float2 o; o.x = aB0 + bo0; o.y = aB1 + bo1; ((float2*)out)[eB] = o; }
                    if (vC) { float2 o; o.x = aC0 + bo0; o.y = aC1 + bo1; ((float2*)out)[eC] = o; }
                    if (vD) { float2 o; o.x = aD0 + bo0; o.y = aD1 + bo1; ((float2*)out)[eD] = o; }
                }
                pA = nA; pB = nB; pC = nC; pD = nD;
                iA = kA; iB = kB; iC = kC; iD = kD;
            }
        }
    }
}

extern "C" void kernel_launch(void* const* d_in, const int* in_sizes, int n_in,
                              void* d_out, int out_size, void* d_ws, size_t ws_size,
                              hipStream_t stream) {
    const float* x   = (const float*)d_in[0];
    const int*   ei  = (const int*)d_in[1];
    const float* W1l = (const float*)d_in[2];
    const float* b1l = (const float*)d_in[3];
    const float* W1r = (const float*)d_in[4];
    const float* W2l = (const float*)d_in[5];
    const float* b2l = (const float*)d_in[6];
    const float* W2r = (const float*)d_in[7];
    const float* Wm1 = (const float*)d_in[8];
    const float* bm1 = (const float*)d_in[9];
    const float* Wm2 = (const float*)d_in[10];
    const float* bm2 = (const float*)d_in[11];

    const int N = in_sizes[0] / IN_DIM;   // 50000
    const int E = in_sizes[1] / 2;        // 800000
    const int* src = ei;
    const int* dst = ei + E;
    const int NB = (N + SCAN_CHUNK - 1) / SCAN_CHUNK;

    // ---- workspace ----
    char* ws = (char*)d_ws;
    size_t off = 0;
    auto alloc = [&](size_t bytes) { void* p = ws + off; off = (off + bytes + 255) & ~(size_t)255; return p; };
    int* deg       = (int*)alloc((size_t)N * 4);
    int* row_start = (int*)alloc((size_t)N * 4);
    int* pos_e     = (int*)alloc((size_t)E * 4);
    int* partials  = (int*)alloc((size_t)(NB + 1) * 4);
    int2* csr      = (int2*)alloc((size_t)E * 8);
    size_t matB = (size_t)N * HID * sizeof(ushort_t);          // 25.6 MB
    ushort_t* xb   = (ushort_t*)alloc(matB);
    ushort_t* h1b  = (ushort_t*)alloc(matB);
    ushort_t* Pb   = (ushort_t*)alloc(matB);
    ushort_t* Qb   = (ushort_t*)alloc(matB);
    size_t wfB  = (size_t)8 * 16 * 512 * sizeof(ushort_t);      // 128 KB (single plane)
    ushort_t* WF1l = (ushort_t*)alloc(wfB);
    ushort_t* WF1r = (ushort_t*)alloc(wfB);
    ushort_t* WF2l = (ushort_t*)alloc(wfB);
    ushort_t* WF2r = (ushort_t*)alloc(wfB);
    ushort_t* WFm  = (ushort_t*)alloc(wfB * 2);                 // nbTot=32
    float* out = (float*)d_out;

    int mrows = (N + 63) / 64;
    const int SB = (E + 255) / 256;           // scatter blocks

    // ---- CSR build (single atomic pass) + cast + weight prep ----
    hipMemsetAsync(deg, 0, (size_t)N * 4, stream);
    k_count_pos<<<(E + 255) / 256, 256, 0, stream>>>(dst, deg, pos_e, E);
    k_chunk_sum<<<NB, 64, 0, stream>>>(deg, partials, N);
    k_scan_partials<<<1, 64, 0, stream>>>(partials, NB);
    k_scan_chunks<<<NB, 64, 0, stream>>>(deg, partials, row_start, N);
    k_cast<<<(N * HID / 4 + 255) / 256, 256, 0, stream>>>(x, xb, N * HID / 4);
    k_scatter_wprep<<<SB + 192, 256, 0, stream>>>(src, dst, pos_e, row_start, csr, E, SB,
                                                  W1l, WF1l, W1r, WF1r, W2l, WF2l, W2r, WF2r,
                                                  Wm1, WFm);

    // ---- conv1 (fused gather + dual GEMM) ----
    k_conv<0><<<mrows, 512, 0, stream>>>(xb, csr, row_start, deg, WF1l, WF1r, b1l, N, h1b,
                                         nullptr, nullptr, nullptr);

    // ---- conv2 + P|Q GEMM fused ----
    k_conv<1><<<mrows, 512, 0, stream>>>(h1b, csr, row_start, deg, WF2l, WF2r, b2l, N, nullptr,
                                         WFm, Pb, Qb);

    // ---- edge MLP (persistent waves) ----
    const int EB = 2048;                  // 8 blocks/CU
    k_edge<<<EB, 256, 0, stream>>>(Pb, Qb, csr, row_start, deg, bm1, Wm2, bm2, out, N, EB * 4);
}